// Round 1
// baseline (196.251 us; speedup 1.0000x reference)
//
#include <hip/hip_runtime.h>
#include <math.h>

#define FEAT 2048
#define NBINS 32
#define NROWS 16384
#define NCLS 64          // batch: env = i % 64
#define STAT_BLOCKS 64
#define ROWS_PER_STAT (NROWS / STAT_BLOCKS)   // 256

// ---------------- K1: per-block partial column sums / sumsq ----------------
// grid 64 x 256. Block b owns rows [b*256, b*256+256).
// Thread t owns float4 column-groups t and t+256 (8 columns).
__global__ __launch_bounds__(256) void k1_stats(const float* __restrict__ x,
                                                float* __restrict__ pS1,
                                                float* __restrict__ pS2) {
    const int b = blockIdx.x, t = threadIdx.x;
    const float4* xb = reinterpret_cast<const float4*>(x) + (size_t)b * ROWS_PER_STAT * (FEAT / 4);
    float4 s1a = make_float4(0.f, 0.f, 0.f, 0.f);
    float4 s1b = make_float4(0.f, 0.f, 0.f, 0.f);
    float4 s2a = make_float4(0.f, 0.f, 0.f, 0.f);
    float4 s2b = make_float4(0.f, 0.f, 0.f, 0.f);
    for (int r = 0; r < ROWS_PER_STAT; ++r) {
        const float4* row = xb + (size_t)r * (FEAT / 4);
        float4 va = row[t];
        float4 vb = row[t + 256];
        s1a.x += va.x; s1a.y += va.y; s1a.z += va.z; s1a.w += va.w;
        s2a.x += va.x * va.x; s2a.y += va.y * va.y; s2a.z += va.z * va.z; s2a.w += va.w * va.w;
        s1b.x += vb.x; s1b.y += vb.y; s1b.z += vb.z; s1b.w += vb.w;
        s2b.x += vb.x * vb.x; s2b.y += vb.y * vb.y; s2b.z += vb.z * vb.z; s2b.w += vb.w * vb.w;
    }
    float4* o1 = reinterpret_cast<float4*>(pS1 + (size_t)b * FEAT);
    float4* o2 = reinterpret_cast<float4*>(pS2 + (size_t)b * FEAT);
    o1[t] = s1a; o1[t + 256] = s1b;
    o2[t] = s2a; o2[t + 256] = s2b;
}

// ---------------- K2: finalize stats (fp64), build Q = P/sigma, ms = mean/sigma
// grid 8 x 256; one thread per feature column.
__global__ __launch_bounds__(256) void k2_final(const float* __restrict__ pS1,
                                                const float* __restrict__ pS2,
                                                const float* __restrict__ P,
                                                float* __restrict__ Q,
                                                float* __restrict__ ms) {
    const int c = blockIdx.x * 256 + threadIdx.x;
    double S1 = 0.0, S2 = 0.0;
    for (int k = 0; k < STAT_BLOCKS; ++k) {
        S1 += (double)pS1[(size_t)k * FEAT + c];
        S2 += (double)pS2[(size_t)k * FEAT + c];
    }
    const double n = (double)NROWS;
    const double bm = S1 / n;
    const double bv = (S2 - S1 * S1 / n) / (n - 1.0);   // ddof=1
    const double tot = 1e-4 + n;
    const double mean = bm * (n / tot);
    const double m2 = 1e-4 + bv * n + bm * bm * (1e-4 * n / tot);
    const double var = m2 / tot;
    const double isig = 1.0 / sqrt(var + 1e-8);
    ms[c] = (float)(mean * isig);
    #pragma unroll
    for (int bb = 0; bb < NBINS; ++bb) {
        Q[(size_t)c * NBINS + bb] = (float)((double)P[(size_t)c * NBINS + bb] * isig);
    }
}

// ---------------- K2b: offset[b] = sum_f ms[f] * P[f][b]  (fp64, fixed order)
__global__ __launch_bounds__(256) void k2b_offset(const float* __restrict__ ms,
                                                  const float* __restrict__ P,
                                                  float* __restrict__ offs) {
    __shared__ double sh[256][NBINS];
    const int t = threadIdx.x;
    double acc[NBINS];
    #pragma unroll
    for (int b = 0; b < NBINS; ++b) acc[b] = 0.0;
    for (int c = t; c < FEAT; c += 256) {
        const double m = (double)ms[c];
        #pragma unroll
        for (int b = 0; b < NBINS; ++b)
            acc[b] += m * (double)P[(size_t)c * NBINS + b];
    }
    #pragma unroll
    for (int b = 0; b < NBINS; ++b) sh[t][b] = acc[b];
    __syncthreads();
    if (t < NBINS) {
        double s = 0.0;
        for (int r = 0; r < 256; ++r) s += sh[r][t];
        offs[t] = (float)s;
    }
}

// ---------------- K3: projection + sign hash ----------------
// grid 256 x 256 (4 waves). Block owns 64 rows; wave w owns bins [w*8, w*8+8);
// lane l owns row l. x-tile and Q-chunk staged in LDS; Q reads wave-uniform.
#define FC 128
#define XPITCH 132
__global__ __launch_bounds__(256) void k3_project(const float* __restrict__ x,
                                                  const float* __restrict__ Q,
                                                  const float* __restrict__ offs,
                                                  unsigned int* __restrict__ hout) {
    __shared__ float xs[64][XPITCH];
    __shared__ float qs[FC][NBINS];
    __shared__ unsigned int shm[4][64];
    const int t = threadIdx.x;
    const int wave = t >> 6;
    const int lane = t & 63;
    const int r0 = blockIdx.x * 64;
    const int b0 = wave * 8;

    float acc[8];
    #pragma unroll
    for (int k = 0; k < 8; ++k) acc[k] = 0.f;

    for (int fc = 0; fc < FEAT; fc += FC) {
        __syncthreads();   // previous chunk fully consumed before overwrite
        // stage x tile: 64 rows x FC cols = 2048 float4; 8 per thread
        #pragma unroll
        for (int j = 0; j < 8; ++j) {
            const int q = t + 256 * j;       // 0..2047
            const int rr = q >> 5;           // /32 float4s per row
            const int f4 = q & 31;
            const float4 v = *reinterpret_cast<const float4*>(
                x + (size_t)(r0 + rr) * FEAT + fc + f4 * 4);
            *reinterpret_cast<float4*>(&xs[rr][f4 * 4]) = v;
        }
        // stage Q chunk: FC x 32 = 1024 float4; 4 per thread
        #pragma unroll
        for (int j = 0; j < 4; ++j) {
            const int q = t + 256 * j;       // 0..1023
            *reinterpret_cast<float4*>(&qs[0][0] + (size_t)q * 4) =
                *reinterpret_cast<const float4*>(Q + (size_t)fc * NBINS + (size_t)q * 4);
        }
        __syncthreads();
        #pragma unroll 4
        for (int ff4 = 0; ff4 < FC / 4; ++ff4) {
            const float4 xv = *reinterpret_cast<const float4*>(&xs[lane][ff4 * 4]);
            const float xva[4] = {xv.x, xv.y, xv.z, xv.w};
            #pragma unroll
            for (int k = 0; k < 4; ++k) {
                const int ff = ff4 * 4 + k;
                const float4 q0 = *reinterpret_cast<const float4*>(&qs[ff][b0]);
                const float4 q1 = *reinterpret_cast<const float4*>(&qs[ff][b0 + 4]);
                const float xvk = xva[k];
                acc[0] += xvk * q0.x; acc[1] += xvk * q0.y;
                acc[2] += xvk * q0.z; acc[3] += xvk * q0.w;
                acc[4] += xvk * q1.x; acc[5] += xvk * q1.y;
                acc[6] += xvk * q1.z; acc[7] += xvk * q1.w;
            }
        }
    }
    // sign bits for this wave's 8 bins
    unsigned int m = 0;
    #pragma unroll
    for (int k = 0; k < 8; ++k) {
        m |= (acc[k] > offs[b0 + k]) ? (1u << k) : 0u;
    }
    shm[wave][lane] = m;
    __syncthreads();
    if (wave == 0) {
        const unsigned int h = shm[0][lane] | (shm[1][lane] << 8) |
                               (shm[2][lane] << 16) | (shm[3][lane] << 24);
        const int i = r0 + lane;
        hout[(i & (NCLS - 1)) * (NROWS / NCLS) + (i >> 6)] = h;  // class-major
    }
}

// ---------------- K4: per-class prefix occurrence count -> reward ----------------
// grid 64 x 256. Class c = i % 64 holds elements i = c + 64*t, t increasing = original order.
__global__ __launch_bounds__(256) void k4_count(const unsigned int* __restrict__ hcls,
                                                float* __restrict__ out) {
    __shared__ unsigned int hh[256];
    const int c = blockIdx.x, t = threadIdx.x;
    hh[t] = hcls[(size_t)c * 256 + t];
    __syncthreads();
    const unsigned int mine = hh[t];
    int cnt = 1;
    for (int j = 0; j < 256; ++j) {
        cnt += (j < t && hh[j] == mine) ? 1 : 0;
    }
    out[(size_t)t * NCLS + c] = 1.0f / sqrtf((float)cnt);
}

extern "C" void kernel_launch(void* const* d_in, const int* in_sizes, int n_in,
                              void* d_out, int out_size, void* d_ws, size_t ws_size,
                              hipStream_t stream) {
    const float* x = (const float*)d_in[0];          // 64*256*2048
    const float* P = (const float*)d_in[1];          // 2048*32
    float* out = (float*)d_out;                      // 16384
    float* ws = (float*)d_ws;

    float* pS1 = ws;                                  // 64*2048 = 131072
    float* pS2 = ws + 131072;                         // 131072
    float* Q   = ws + 262144;                         // 65536
    float* ms  = ws + 327680;                         // 2048
    float* offs = ws + 329728;                        // 32
    unsigned int* h = (unsigned int*)(ws + 329760);   // 16384 u32

    k1_stats<<<STAT_BLOCKS, 256, 0, stream>>>(x, pS1, pS2);
    k2_final<<<FEAT / 256, 256, 0, stream>>>(pS1, pS2, P, Q, ms);
    k2b_offset<<<1, 256, 0, stream>>>(ms, P, offs);
    k3_project<<<NROWS / 64, 256, 0, stream>>>(x, Q, offs, h);
    k4_count<<<NCLS, 256, 0, stream>>>(h, out);
}

// Round 2
// 80.678 us; speedup vs baseline: 2.4325x; 2.4325x over previous
//
#include <hip/hip_runtime.h>
#include <math.h>

#define FEAT 2048
#define NBINS 32
#define NROWS 16384
#define NCLS 64

typedef __attribute__((ext_vector_type(8))) short short8;
typedef __attribute__((ext_vector_type(4))) float f32x4;

static __device__ __forceinline__ unsigned short f2bf(float f) {
    unsigned u = __float_as_uint(f);
    unsigned r = (u + 0x7FFFu + ((u >> 16) & 1u)) >> 16;   // RNE
    return (unsigned short)r;
}

// ---------------- K1: per-block partial column sums / sumsq ----------------
// grid SB blocks x 256 threads. Block b owns rpb rows. Thread t owns float4
// column-groups t and t+256.
__global__ __launch_bounds__(256) void k1_stats(const float* __restrict__ x,
                                                float* __restrict__ pS1,
                                                float* __restrict__ pS2,
                                                int rpb) {
    const int b = blockIdx.x, t = threadIdx.x;
    const float4* xb = reinterpret_cast<const float4*>(x) + (size_t)b * rpb * (FEAT / 4);
    float4 s1a = make_float4(0.f, 0.f, 0.f, 0.f);
    float4 s1b = make_float4(0.f, 0.f, 0.f, 0.f);
    float4 s2a = make_float4(0.f, 0.f, 0.f, 0.f);
    float4 s2b = make_float4(0.f, 0.f, 0.f, 0.f);
    for (int r = 0; r < rpb; ++r) {
        const float4 va = xb[(size_t)r * (FEAT / 4) + t];
        const float4 vb = xb[(size_t)r * (FEAT / 4) + t + 256];
        s1a.x += va.x; s1a.y += va.y; s1a.z += va.z; s1a.w += va.w;
        s2a.x += va.x * va.x; s2a.y += va.y * va.y; s2a.z += va.z * va.z; s2a.w += va.w * va.w;
        s1b.x += vb.x; s1b.y += vb.y; s1b.z += vb.z; s1b.w += vb.w;
        s2b.x += vb.x * vb.x; s2b.y += vb.y * vb.y; s2b.z += vb.z * vb.z; s2b.w += vb.w * vb.w;
    }
    float4* o1 = reinterpret_cast<float4*>(pS1 + (size_t)b * FEAT);
    float4* o2 = reinterpret_cast<float4*>(pS2 + (size_t)b * FEAT);
    o1[t] = s1a; o1[t + 256] = s1b;
    o2[t] = s2a; o2[t + 256] = s2b;
}

// ---------------- K2: finalize stats (fp64), build ms + QT (bf16, transposed)
// grid 64 blocks x 256. Block covers 32 columns; 8 segments of SB/8 partials.
__global__ __launch_bounds__(256) void k2_final(const float* __restrict__ pS1,
                                                const float* __restrict__ pS2,
                                                const float* __restrict__ P,
                                                float* __restrict__ ms,
                                                unsigned short* __restrict__ QT,
                                                int SB) {
    __shared__ double sh1[8][32];
    __shared__ double sh2[8][32];
    const int t = threadIdx.x;
    const int ci = t & 31, seg = t >> 5;
    const int c = blockIdx.x * 32 + ci;
    const int segN = SB >> 3;
    double S1 = 0.0, S2 = 0.0;
    for (int i = 0; i < segN; ++i) {
        const int k = seg * segN + i;
        S1 += (double)pS1[(size_t)k * FEAT + c];
        S2 += (double)pS2[(size_t)k * FEAT + c];
    }
    sh1[seg][ci] = S1; sh2[seg][ci] = S2;
    __syncthreads();
    if (t < 32) {
        double s1 = 0.0, s2 = 0.0;
        #pragma unroll
        for (int s = 0; s < 8; ++s) { s1 += sh1[s][t]; s2 += sh2[s][t]; }
        const int cc = blockIdx.x * 32 + t;
        const double n = (double)NROWS;
        const double bm = s1 / n;
        const double bv = (s2 - s1 * s1 / n) / (n - 1.0);
        const double tot = 1e-4 + n;
        const double mean = bm * (n / tot);
        const double m2 = 1e-4 + bv * n + bm * bm * (1e-4 * n / tot);
        const double var = m2 / tot;
        const double isig = 1.0 / sqrt(var + 1e-8);
        ms[cc] = (float)(mean * isig);
        for (int b = 0; b < NBINS; ++b) {
            QT[(size_t)b * FEAT + cc] = f2bf((float)((double)P[(size_t)cc * NBINS + b] * isig));
        }
    }
}

// ---------------- K2b: offs[b] = sum_f ms[f] * P[f][b] ----------------
// grid 32 blocks (one per bin) x 256.
__global__ __launch_bounds__(256) void k2b_offset(const float* __restrict__ ms,
                                                  const float* __restrict__ P,
                                                  float* __restrict__ offs) {
    __shared__ double sh[256];
    const int b = blockIdx.x, t = threadIdx.x;
    double s = 0.0;
    for (int f = t; f < FEAT; f += 256) s += (double)ms[f] * (double)P[(size_t)f * NBINS + b];
    sh[t] = s;
    __syncthreads();
    for (int st = 128; st > 0; st >>= 1) {
        if (t < st) sh[t] += sh[t + st];
        __syncthreads();
    }
    if (t == 0) offs[b] = (float)sh[0];
}

// ---------------- K3: bf16 MFMA projection + sign hash ----------------
// grid 256 x 256 (4 waves). Block owns 64 rows; wave w owns rows w*16..w*16+16,
// all 32 bins (2 accumulator frags). K-loop: 16 chunks of 128 features,
// software-pipelined global->reg->LDS staging with XOR granule swizzle.
__global__ __launch_bounds__(256) void k3_mfma(const float* __restrict__ x,
                                               const unsigned short* __restrict__ QT,
                                               const float* __restrict__ offs,
                                               unsigned int* __restrict__ hout) {
    __shared__ unsigned short xbf[64 * 128];   // [row][128 k] bf16, granule-swizzled
    __shared__ unsigned short qbf[32 * 128];   // [bin][128 k] bf16, granule-swizzled
    const int t = threadIdx.x;
    const int w = t >> 6, l = t & 63;
    const int lrow = l & 15, lk = l >> 4;      // D: row=(lk*4+reg), col=lrow
    const int bid = blockIdx.x;
    const int r0 = bid * 64;

    f32x4 acc0 = {0.f, 0.f, 0.f, 0.f};
    f32x4 acc1 = {0.f, 0.f, 0.f, 0.f};

    // staging index precompute (x: q = t + 256*j -> row=q>>5, c4=q&31)
    float4 xr[2][8];
    int4 qr[2][2];

    // ---- prologue: load chunk 0 ----
    #pragma unroll
    for (int j = 0; j < 8; ++j) {
        const int q = t + 256 * j;
        const int row = q >> 5, c4 = q & 31;
        xr[0][j] = *reinterpret_cast<const float4*>(x + (size_t)(r0 + row) * FEAT + c4 * 4);
    }
    #pragma unroll
    for (int j = 0; j < 2; ++j) {
        const int G = t + 256 * j;
        const int bin = G >> 4, g = G & 15;
        const int gsrc = g ^ (bin & 7);
        qr[0][j] = *reinterpret_cast<const int4*>(QT + (size_t)bin * FEAT + gsrc * 8);
    }

    #pragma unroll
    for (int ch = 0; ch < 16; ++ch) {
        const int cur = ch & 1, nxt = cur ^ 1;
        __syncthreads();   // previous chunk's MFMA reads complete
        // issue next chunk's global loads (overlap with stores + MFMA)
        if (ch < 15) {
            #pragma unroll
            for (int j = 0; j < 8; ++j) {
                const int q = t + 256 * j;
                const int row = q >> 5, c4 = q & 31;
                xr[nxt][j] = *reinterpret_cast<const float4*>(
                    x + (size_t)(r0 + row) * FEAT + (ch + 1) * 128 + c4 * 4);
            }
            #pragma unroll
            for (int j = 0; j < 2; ++j) {
                const int G = t + 256 * j;
                const int bin = G >> 4, g = G & 15;
                const int gsrc = g ^ (bin & 7);
                qr[nxt][j] = *reinterpret_cast<const int4*>(
                    QT + (size_t)bin * FEAT + (ch + 1) * 128 + gsrc * 8);
            }
        }
        // store current chunk to LDS (cvt f32->bf16, XOR-swizzled granules)
        #pragma unroll
        for (int j = 0; j < 8; ++j) {
            const int q = t + 256 * j;
            const int row = q >> 5, c4 = q & 31;
            const int g = c4 >> 1, half = c4 & 1;
            const int gs = g ^ (row & 7);
            const float4 v = xr[cur][j];
            int2 pk;
            pk.x = (int)f2bf(v.x) | ((int)f2bf(v.y) << 16);
            pk.y = (int)f2bf(v.z) | ((int)f2bf(v.w) << 16);
            *reinterpret_cast<int2*>(&xbf[row * 128 + gs * 8 + half * 4]) = pk;
        }
        #pragma unroll
        for (int j = 0; j < 2; ++j) {
            const int G = t + 256 * j;
            const int bin = G >> 4, g = G & 15;
            *reinterpret_cast<int4*>(&qbf[bin * 128 + g * 8]) = qr[cur][j];
        }
        __syncthreads();
        // compute: 4 k-steps of 32
        #pragma unroll
        for (int ks = 0; ks < 4; ++ks) {
            const int gsw = (ks * 4 + lk) ^ (lrow & 7);
            const short8 a = *reinterpret_cast<const short8*>(
                &xbf[(w * 16 + lrow) * 128 + gsw * 8]);
            const short8 b0 = *reinterpret_cast<const short8*>(
                &qbf[lrow * 128 + gsw * 8]);
            const short8 b1 = *reinterpret_cast<const short8*>(
                &qbf[(16 + lrow) * 128 + gsw * 8]);
            acc0 = __builtin_amdgcn_mfma_f32_16x16x32_bf16(a, b0, acc0, 0, 0, 0);
            acc1 = __builtin_amdgcn_mfma_f32_16x16x32_bf16(a, b1, acc1, 0, 0, 0);
        }
    }

    // ---- epilogue: sign bits -> 32-bit hash via ballot, write class-major ----
    const float o0 = offs[lrow];
    const float o1 = offs[16 + lrow];
    #pragma unroll
    for (int r = 0; r < 4; ++r) {
        const unsigned long long m0 = __ballot(acc0[r] > o0);
        const unsigned long long m1 = __ballot(acc1[r] > o1);
        if (lrow == 0) {
            const unsigned int h =
                (unsigned int)((m0 >> (16 * lk)) & 0xFFFFull) |
                ((unsigned int)((m1 >> (16 * lk)) & 0xFFFFull) << 16);
            const int irow = w * 16 + lk * 4 + r;   // local row 0..63 == i & 63
            hout[(size_t)irow * 256 + bid] = h;     // class-major [class][slot]
        }
    }
}

// ---------------- K4: per-class prefix occurrence count -> reward ----------------
__global__ __launch_bounds__(256) void k4_count(const unsigned int* __restrict__ hcls,
                                                float* __restrict__ out) {
    __shared__ unsigned int hh[256];
    const int c = blockIdx.x, t = threadIdx.x;
    hh[t] = hcls[(size_t)c * 256 + t];
    __syncthreads();
    const unsigned int mine = hh[t];
    int cnt = 1;
    for (int j = 0; j < 256; ++j) {
        cnt += (j < t && hh[j] == mine) ? 1 : 0;
    }
    out[(size_t)t * NCLS + c] = 1.0f / sqrtf((float)cnt);
}

extern "C" void kernel_launch(void* const* d_in, const int* in_sizes, int n_in,
                              void* d_out, int out_size, void* d_ws, size_t ws_size,
                              hipStream_t stream) {
    const float* x = (const float*)d_in[0];   // 64*256*2048 f32
    const float* P = (const float*)d_in[1];   // 2048*32 f32
    float* out = (float*)d_out;               // 16384 f32
    float* ws = (float*)d_ws;

    // ws tiering: prefer 256 stat blocks (4.4 MB), fall back to 64 (1.25 MB)
    const int SB = (ws_size >= (size_t)4600000) ? 256 : 64;
    const int rpb = NROWS / SB;

    float* pS1 = ws;                               // SB*2048
    float* pS2 = pS1 + (size_t)SB * FEAT;          // SB*2048
    float* ms = pS2 + (size_t)SB * FEAT;           // 2048
    float* offsB = ms + FEAT;                      // 32
    unsigned short* QT = (unsigned short*)(offsB + NBINS);      // 2048*32 bf16
    unsigned int* h = (unsigned int*)(QT + (size_t)FEAT * NBINS); // 16384 u32

    k1_stats<<<SB, 256, 0, stream>>>(x, pS1, pS2, rpb);
    k2_final<<<64, 256, 0, stream>>>(pS1, pS2, P, ms, QT, SB);
    k2b_offset<<<32, 256, 0, stream>>>(ms, P, offsB);
    k3_mfma<<<256, 256, 0, stream>>>(x, QT, offsB, h);
    k4_count<<<NCLS, 256, 0, stream>>>(h, out);
}

// Round 3
// 70.345 us; speedup vs baseline: 2.7898x; 1.1469x over previous
//
#include <hip/hip_runtime.h>
#include <math.h>

#define FEAT 2048
#define NBINS 32
#define NROWS 16384
#define NCLS 64
#define SB 256          // stat blocks == projection tiles
#define RPB 64          // rows per block/tile

typedef __attribute__((ext_vector_type(8))) short short8;
typedef __attribute__((ext_vector_type(4))) float f32x4;

// packed RNE f32x2 -> bf16x2
static __device__ __forceinline__ unsigned int pk2bf(float a, float b) {
    unsigned ua = __float_as_uint(a);
    unsigned ub = __float_as_uint(b);
    ua = (ua + 0x7FFFu + ((ua >> 16) & 1u)) >> 16;
    ub = (ub + 0x7FFFu + ((ub >> 16) & 1u)) & 0xFFFF0000u;
    return ua | ub;
}

// ---------------- K1: partial column sums/sumsq + bf16 fragment-ordered x ----
// grid 256 x 256. Block b owns rows [b*64, b*64+64) == projection tile b.
// Thread t owns float4 col-groups t and t+256 (cols 4t.. and 1024+4t..).
// Fragment layout (256KB per tile): byte = ((w*16+ch)*4+ks)*1024 + lane*16 + off*2
//   where lane = (row&15) + 16*((k>>3)&3), w=row>>4, ch=k>>7, ks=(k>>5)&3, off=k&7.
__global__ __launch_bounds__(256) void k1_stats(const float* __restrict__ x,
                                                float* __restrict__ pS1,
                                                float* __restrict__ pS2,
                                                unsigned int* __restrict__ xbf) {
    const int b = blockIdx.x, t = threadIdx.x;
    const float4* xb = reinterpret_cast<const float4*>(x) + (size_t)b * RPB * (FEAT / 4);
    const int k0a = 4 * t;
    const int k0b = 4 * t + 1024;
    const int cpA = ((k0a >> 7) * 4 + ((k0a >> 5) & 3)) * 1024 + (((k0a >> 3) & 3) << 8) + ((k0a & 7) << 1);
    const int cpB = ((k0b >> 7) * 4 + ((k0b >> 5) & 3)) * 1024 + (((k0b >> 3) & 3) << 8) + ((k0b & 7) << 1);
    char* tile = reinterpret_cast<char*>(xbf) + (size_t)b * 262144;

    float4 s1a = make_float4(0.f,0.f,0.f,0.f), s1b = make_float4(0.f,0.f,0.f,0.f);
    float4 s2a = make_float4(0.f,0.f,0.f,0.f), s2b = make_float4(0.f,0.f,0.f,0.f);
    for (int r = 0; r < RPB; ++r) {
        const float4 va = xb[(size_t)r * (FEAT / 4) + t];
        const float4 vb = xb[(size_t)r * (FEAT / 4) + t + 256];
        s1a.x += va.x; s1a.y += va.y; s1a.z += va.z; s1a.w += va.w;
        s2a.x += va.x * va.x; s2a.y += va.y * va.y; s2a.z += va.z * va.z; s2a.w += va.w * va.w;
        s1b.x += vb.x; s1b.y += vb.y; s1b.z += vb.z; s1b.w += vb.w;
        s2b.x += vb.x * vb.x; s2b.y += vb.y * vb.y; s2b.z += vb.z * vb.z; s2b.w += vb.w * vb.w;
        const int rp = (r >> 4) * 65536 + (r & 15) * 16;
        uint2 pa, pb;
        pa.x = pk2bf(va.x, va.y); pa.y = pk2bf(va.z, va.w);
        pb.x = pk2bf(vb.x, vb.y); pb.y = pk2bf(vb.z, vb.w);
        *reinterpret_cast<uint2*>(tile + cpA + rp) = pa;
        *reinterpret_cast<uint2*>(tile + cpB + rp) = pb;
    }
    float4* o1 = reinterpret_cast<float4*>(pS1 + (size_t)b * FEAT);
    float4* o2 = reinterpret_cast<float4*>(pS2 + (size_t)b * FEAT);
    o1[t] = s1a; o1[t + 256] = s1b;
    o2[t] = s2a; o2[t + 256] = s2b;
}

// ---------------- K2: finalize stats (fp64); ms; Q in B-fragment order -------
// grid 64 x 256. Block covers 32 k-columns == one (ch,ks) group -> writes the
// two 1KB fragments (nb=0,1) for that group.
__global__ __launch_bounds__(256) void k2_final(const float* __restrict__ pS1,
                                                const float* __restrict__ pS2,
                                                const float* __restrict__ P,
                                                float* __restrict__ ms,
                                                unsigned int* __restrict__ QTf) {
    __shared__ double sh1[8][32];
    __shared__ double sh2[8][32];
    __shared__ float isig_sh[32];
    const int t = threadIdx.x;
    const int ci = t & 31, seg = t >> 5;
    const int c = blockIdx.x * 32 + ci;
    double S1 = 0.0, S2 = 0.0;
    for (int i = 0; i < 32; ++i) {
        const int k = seg * 32 + i;
        S1 += (double)pS1[(size_t)k * FEAT + c];
        S2 += (double)pS2[(size_t)k * FEAT + c];
    }
    sh1[seg][ci] = S1; sh2[seg][ci] = S2;
    __syncthreads();
    if (t < 32) {
        double s1 = 0.0, s2 = 0.0;
        #pragma unroll
        for (int s = 0; s < 8; ++s) { s1 += sh1[s][t]; s2 += sh2[s][t]; }
        const int cc = blockIdx.x * 32 + t;
        const double n = (double)NROWS;
        const double bm = s1 / n;
        const double bv = (s2 - s1 * s1 / n) / (n - 1.0);
        const double tot = 1e-4 + n;
        const double mean = bm * (n / tot);
        const double m2 = 1e-4 + bv * n + bm * bm * (1e-4 * n / tot);
        const double var = m2 / tot;
        const double isig = 1.0 / sqrt(var + 1e-8);
        ms[cc] = (float)(mean * isig);
        isig_sh[t] = (float)isig;
    }
    __syncthreads();
    // write fragments: nb = t>>7, lane = (t&127)>>1, half = t&1
    const int nb = t >> 7;
    const int lane = (t & 127) >> 1;
    const int half = t & 1;
    const int lrow = lane & 15, lk = lane >> 4;
    const int bin = nb * 16 + lrow;
    const int ccl = lk * 8 + half * 4;
    const int cc = blockIdx.x * 32 + ccl;
    unsigned int w0 = pk2bf(P[(size_t)cc * NBINS + bin] * isig_sh[ccl],
                            P[(size_t)(cc + 1) * NBINS + bin] * isig_sh[ccl + 1]);
    unsigned int w1 = pk2bf(P[(size_t)(cc + 2) * NBINS + bin] * isig_sh[ccl + 2],
                            P[(size_t)(cc + 3) * NBINS + bin] * isig_sh[ccl + 3]);
    const int ch = blockIdx.x >> 2, ks = blockIdx.x & 3;
    char* dst = reinterpret_cast<char*>(QTf) +
                (size_t)(((nb * 16 + ch) * 4 + ks) * 1024 + lane * 16 + half * 8);
    uint2 pk; pk.x = w0; pk.y = w1;
    *reinterpret_cast<uint2*>(dst) = pk;
}

// ---------------- K2b: offs[b] = sum_f ms[f] * P[f][b] ----------------
__global__ __launch_bounds__(256) void k2b_offset(const float* __restrict__ ms,
                                                  const float* __restrict__ P,
                                                  float* __restrict__ offs) {
    __shared__ double sh[256];
    const int b = blockIdx.x, t = threadIdx.x;
    double s = 0.0;
    for (int f = t; f < FEAT; f += 256) s += (double)ms[f] * (double)P[(size_t)f * NBINS + b];
    sh[t] = s;
    __syncthreads();
    for (int st = 128; st > 0; st >>= 1) {
        if (t < st) sh[t] += sh[t + st];
        __syncthreads();
    }
    if (t == 0) offs[b] = (float)sh[0];
}

// ---------------- K3: barrier-free MFMA projection + sign hash ----------------
// grid 256 x 256 (4 waves). Wave w: rows bid*64 + w*16 .. +16, all 32 bins.
// A and B fragments are pre-arranged in global memory: each load is one
// wave-contiguous 1KB global_load_dwordx4. No LDS, no __syncthreads.
__global__ __launch_bounds__(256) void k3_mfma(const unsigned int* __restrict__ xbf,
                                               const unsigned int* __restrict__ QTf,
                                               const float* __restrict__ offs,
                                               unsigned int* __restrict__ hout) {
    const int t = threadIdx.x;
    const int w = t >> 6, l = t & 63;
    const int lrow = l & 15, lk = l >> 4;
    const int bid = blockIdx.x;

    const short8* ap  = reinterpret_cast<const short8*>(xbf) + (size_t)bid * 16384 + w * 4096 + l;
    const short8* b0p = reinterpret_cast<const short8*>(QTf) + l;
    const short8* b1p = b0p + 4096;

    f32x4 acc0 = {0.f, 0.f, 0.f, 0.f};
    f32x4 acc1 = {0.f, 0.f, 0.f, 0.f};

    #pragma unroll 8
    for (int ss = 0; ss < 64; ++ss) {
        const short8 a  = ap[ss * 64];
        const short8 b0 = b0p[ss * 64];
        const short8 b1 = b1p[ss * 64];
        acc0 = __builtin_amdgcn_mfma_f32_16x16x32_bf16(a, b0, acc0, 0, 0, 0);
        acc1 = __builtin_amdgcn_mfma_f32_16x16x32_bf16(a, b1, acc1, 0, 0, 0);
    }

    const float o0 = offs[lrow];
    const float o1 = offs[16 + lrow];
    #pragma unroll
    for (int r = 0; r < 4; ++r) {
        const unsigned long long m0 = __ballot(acc0[r] > o0);
        const unsigned long long m1 = __ballot(acc1[r] > o1);
        if (lrow == 0) {
            const unsigned int h =
                (unsigned int)((m0 >> (16 * lk)) & 0xFFFFull) |
                ((unsigned int)((m1 >> (16 * lk)) & 0xFFFFull) << 16);
            const int irow = w * 16 + lk * 4 + r;       // == i & 63 (class)
            hout[(size_t)irow * 256 + bid] = h;         // class-major
        }
    }
}

// ---------------- K4: per-class prefix occurrence count -> reward ----------------
__global__ __launch_bounds__(256) void k4_count(const unsigned int* __restrict__ hcls,
                                                float* __restrict__ out) {
    __shared__ unsigned int hh[256];
    const int c = blockIdx.x, t = threadIdx.x;
    hh[t] = hcls[(size_t)c * 256 + t];
    __syncthreads();
    const unsigned int mine = hh[t];
    int cnt = 1;
    for (int j = 0; j < 256; ++j) {
        cnt += (j < t && hh[j] == mine) ? 1 : 0;
    }
    out[(size_t)t * NCLS + c] = 1.0f / sqrtf((float)cnt);
}

extern "C" void kernel_launch(void* const* d_in, const int* in_sizes, int n_in,
                              void* d_out, int out_size, void* d_ws, size_t ws_size,
                              hipStream_t stream) {
    const float* x = (const float*)d_in[0];   // 64*256*2048 f32
    const float* P = (const float*)d_in[1];   // 2048*32 f32
    float* out = (float*)d_out;               // 16384 f32
    char* ws = (char*)d_ws;

    // layout (bytes): [pS1 2MB][pS2 2MB][ms 8KB][offs 128B][pad][xbf 64MB @8MB]
    //                 [QTf 128KB][h 64KB]   total ~72.2MB (ws is 512MB)
    float* pS1 = (float*)(ws);
    float* pS2 = (float*)(ws + (size_t)SB * FEAT * 4);
    float* ms  = (float*)(ws + (size_t)2 * SB * FEAT * 4);
    float* offsB = ms + FEAT;
    unsigned int* xbf = (unsigned int*)(ws + (size_t)8 * 1024 * 1024);
    unsigned int* QTf = (unsigned int*)(ws + (size_t)8 * 1024 * 1024 + (size_t)64 * 1024 * 1024);
    unsigned int* h   = (unsigned int*)(ws + (size_t)8 * 1024 * 1024 + (size_t)64 * 1024 * 1024 + 131072);

    k1_stats<<<SB, 256, 0, stream>>>(x, pS1, pS2, xbf);
    k2_final<<<64, 256, 0, stream>>>(pS1, pS2, P, ms, QTf);
    k2b_offset<<<32, 256, 0, stream>>>(ms, P, offsB);
    k3_mfma<<<256, 256, 0, stream>>>(xbf, QTf, offsB, h);
    k4_count<<<NCLS, 256, 0, stream>>>(h, out);
}